// Round 15
// baseline (420.003 us; speedup 1.0000x reference)
//
#include <hip/hip_runtime.h>

namespace {
typedef float v2f __attribute__((ext_vector_type(2)));
typedef unsigned u32x2 __attribute__((ext_vector_type(2)));
constexpr int kB = 256;
constexpr int kS = 2048;
constexpr int kV = 10;
constexpr int kE = 32;
constexpr int kH = 64;
constexpr int kO = 10;
constexpr int kT = 16;      // steps per tile (R14 kT=32 regressed; 16 is optimal)
constexpr int kPad = 68;    // LDS row stride in floats (272 B, 16B-aligned)
constexpr int kTiles = kS / kT;   // 128
// Fold tanh's 2x and log2(e) into weights: s = kC*(xw + h.Wh + b), e^{2p} = 2^s
constexpr float kC = 2.885390081777927f;   // 2*log2(e)

// No clamp needed (R12-proven): even for huge |s| the chain exp2->inf/0, rcp,
// fma yields exactly +-1 = tanh's limit.
__device__ __forceinline__ float step_tanh(float s) {
    float e = __builtin_amdgcn_exp2f(s);
    float r = __builtin_amdgcn_rcpf(e + 1.f);
    return fmaf(-2.f, r, 1.f);              // tanh = 1 - 2/(e^{2p}+1)
}

// R8-HW-proven VALU half-exchange; returns both post-swap registers, which
// jointly hold {p, p[l^32]} at every lane.
__device__ __forceinline__ u32x2 plswap(float p) {
    return __builtin_amdgcn_permlane32_swap(__float_as_uint(p),
                                            __float_as_uint(p),
                                            false, false);
}

// Logits with per-lane FIXED output column o = l%10 (lanes 0..59 active):
// Wd[:,o] lives in 64 VGPRs — zero Wd LDS traffic — and the 10 lanes of a
// tl-group read the SAME h-row addresses (LDS broadcast). (R10: small win.)
__device__ __forceinline__ void do_logits(const float* __restrict__ hb,
                                          const float (& __restrict__ wdc)[kH],
                                          float bdv,
                                          float* __restrict__ out, int obase, int l)
{
    if (l >= 60) return;
    #pragma unroll
    for (int p = 0; p < 3; ++p) {
        int f = p * 60 + l;                  // flat (t_local, o), 160 total
        if (f < kT * kO) {
            int tl = f / kO;                 // = p*6 + l/10
            const float4* hb4 = reinterpret_cast<const float4*>(hb + tl * kPad);
            float a0 = bdv, a1 = 0.f, a2 = 0.f, a3 = 0.f;
            #pragma unroll
            for (int c = 0; c < kH / 4; ++c) {
                float4 h4 = hb4[c];
                a0 = fmaf(h4.x, wdc[4 * c + 0], a0);
                a1 = fmaf(h4.y, wdc[4 * c + 1], a1);
                a2 = fmaf(h4.z, wdc[4 * c + 2], a2);
                a3 = fmaf(h4.w, wdc[4 * c + 3], a3);
            }
            out[obase + f] = (a0 + a1) + (a2 + a3);   // coalesced (f = p*60+l)
        }
    }
}

// Wave 0: serial recurrence, split-K (R8-proven): each lane reads only its
// 32-wide k-half (8x ds_read_b128 broadcast), accumulates own output l
// (incl. xw) + partner output l^32; halves merge via permlane32_swap with a
// setup-probed exact combine. R13 diet: full 16-step unroll (immediate LDS
// addressing), tile-head xw burst (latency hides under step-0's h wait).
// R14 lesson (reverted): pre-barrier prefetch serializes INTO the barrier's
// lgkmcnt(0) drain; kT=32's unroll cost exceeds the barrier saving.
// Wave 1: logits for the previous tile, register-held Wd column.
__global__ __launch_bounds__(128, 1)
void rnn_fused(const int* __restrict__ num1, const int* __restrict__ num2,
               const float* __restrict__ embed, const float* __restrict__ Wx,
               const float* __restrict__ Wh, const float* __restrict__ bias,
               const float* __restrict__ Wd, const float* __restrict__ bd,
               float* __restrict__ out)
{
    const int row = blockIdx.x;   // one sequence per block
    const int tid = threadIdx.x;
    const int w   = tid >> 6;     // 0 = recurrence wave, 1 = logits wave
    const int l   = tid & 63;     // lane owns hidden unit l
    const int lx  = l ^ 32;       // split-K partner lane
    const int kbase = (l >> 5) * 32;       // this lane's k-half

    __shared__ __align__(16) float TT[kV * kV][kH];     // kC*(xw+b), 100 rows
    __shared__ __align__(16) float hbuf[2][kT][kPad];   // double-buffered h history

    v2f whcA2[kH / 4], whcB2[kH / 4];   // kC*Wh k-half cols: own l / partner l^32
    float wdc[kH];                      // wave 1: Wd column l%10
    float bdv = 0.f;
    int idx_next = 0;
    bool selx = false;                  // permlane convention (probed)
    const int lane16 = l & 15;
    const int nb = row * kS;
    const int orow = row * (kS * kO);

    if (w == 0) {
        // ---- one-time setup: input-projection table + Wh half-columns ----
        float wxc[2 * kE];
        #pragma unroll
        for (int k = 0; k < 2 * kE; ++k) wxc[k] = Wx[k * kH + l];  // Wx column l
        float bj = bias[l];
        float t1[kV], t2[kV];
        #pragma unroll
        for (int v = 0; v < kV; ++v) {
            float a0 = 0.f, a1 = 0.f;
            #pragma unroll
            for (int k = 0; k < kE; ++k) {
                float e = embed[v * kE + k];   // lane-uniform -> s_load
                a0 = fmaf(e, wxc[k], a0);
                a1 = fmaf(e, wxc[kE + k], a1);
            }
            t1[v] = a0; t2[v] = a1;
        }
        #pragma unroll
        for (int v1 = 0; v1 < kV; ++v1)
            #pragma unroll
            for (int v2 = 0; v2 < kV; ++v2)
                TT[v1 * kV + v2][l] = kC * (t1[v1] + t2[v2] + bj);
        #pragma unroll
        for (int i = 0; i < kH / 4; ++i) {      // 16 packed pairs per table
            v2f ta, tb;
            ta.x = kC * Wh[(kbase + 2 * i)     * kH + l];
            ta.y = kC * Wh[(kbase + 2 * i + 1) * kH + l];
            tb.x = kC * Wh[(kbase + 2 * i)     * kH + lx];
            tb.y = kC * Wh[(kbase + 2 * i + 1) * kH + lx];
            whcA2[i] = ta; whcB2[i] = tb;
        }
        // probe which swap output holds the PARTNER value (per-lane robust)
        {
            u32x2 pr = plswap((float)l);
            selx = (__uint_as_float(pr.x) == (float)lx);
        }
        hbuf[1][kT - 1][l] = 0.f;   // h_{-1}=0: tile 0 broadcast reads this row
        idx_next = num1[nb + lane16] * kV + num2[nb + lane16];   // tile 0 idx
        __builtin_amdgcn_s_setprio(1);   // favor the chain wave in arbitration
    } else {
        const int o = l % kO;            // lanes 60..63 compute but never use
        #pragma unroll
        for (int k = 0; k < kH; ++k) wdc[k] = Wd[k * kO + o];
        bdv = bd[o];
    }
    __syncthreads();

    for (int ti = 0; ti < kTiles; ++ti) {
        if (w == 0) {
            const int idxv = idx_next;
            if (ti + 1 < kTiles) {
                int tt = nb + (ti + 1) * kT + lane16;
                idx_next = num1[tt] * kV + num2[tt];   // prefetch next tile idx
            }
            float* curBase = &hbuf[ti & 1][0][0];
            const float* prevLast = &hbuf[(ti & 1) ^ 1][kT - 1][0];
            // step-0 h loads FIRST (longest latency)...
            float4 q[8];
            {
                const float4* hq0 =
                    reinterpret_cast<const float4*>(prevLast + kbase);
                #pragma unroll
                for (int c = 0; c < 8; ++c) q[c] = hq0[c];
            }
            // ...then the tile's xw burst; its latency hides under the q wait
            float xwr[kT];
            #pragma unroll
            for (int t2 = 0; t2 < kT; ++t2)
                xwr[t2] = TT[__builtin_amdgcn_readlane(idxv, t2)][l];
            #pragma unroll
            for (int tl = 0; tl < kT; ++tl) {
                v2f o0; o0.x = xwr[tl]; o0.y = 0.f;  // xw folded into acc init
                v2f o1 = {0.f, 0.f}, r0 = {0.f, 0.f}, r1 = {0.f, 0.f};
                #pragma unroll
                for (int c = 0; c < 8; ++c) {
                    v2f lo; lo.x = q[c].x; lo.y = q[c].y;
                    v2f hi; hi.x = q[c].z; hi.y = q[c].w;
                    o0 = lo * whcA2[2 * c]     + o0;   // own output, own k-half
                    o1 = hi * whcA2[2 * c + 1] + o1;
                    r0 = lo * whcB2[2 * c]     + r0;   // partner output partial
                    r1 = hi * whcB2[2 * c + 1] + r1;
                }
                v2f rv = r0 + r1;  float pPar = rv.x + rv.y;
                u32x2 sw = plswap(pPar);
                float oth = selx ? __uint_as_float(sw.x)
                                 : __uint_as_float(sw.y);   // exact partner
                v2f ov = o0 + o1;  float pOwn = ov.x + ov.y;   // incl. xw
                float hcur = step_tanh(pOwn + oth);
                curBase[tl * kPad + l] = hcur;   // publish h_t (row tl)
                if (tl + 1 < kT) {               // next step's h loads
                    const float4* hqn = reinterpret_cast<const float4*>(
                        curBase + tl * kPad + kbase);
                    #pragma unroll
                    for (int c = 0; c < 8; ++c) q[c] = hqn[c];
                }
            }
        } else if (ti > 0) {
            do_logits(&hbuf[(ti - 1) & 1][0][0], wdc, bdv, out,
                      orow + (ti - 1) * kT * kO, l);
        }
        __syncthreads();   // publish tile ti history / retire tile ti-1 reads
    }
    if (w == 1)
        do_logits(&hbuf[(kTiles - 1) & 1][0][0], wdc, bdv, out,
                  orow + (kS - kT) * kO, l);
}
} // namespace

extern "C" void kernel_launch(void* const* d_in, const int* in_sizes, int n_in,
                              void* d_out, int out_size, void* d_ws, size_t ws_size,
                              hipStream_t stream) {
    (void)in_sizes; (void)n_in; (void)d_ws; (void)ws_size; (void)out_size;
    rnn_fused<<<dim3(kB), dim3(128), 0, stream>>>(
        (const int*)d_in[0], (const int*)d_in[1],
        (const float*)d_in[2], (const float*)d_in[3],
        (const float*)d_in[4], (const float*)d_in[5],
        (const float*)d_in[6], (const float*)d_in[7],
        (float*)d_out);
}